// Round 5
// baseline (550.778 us; speedup 1.0000x reference)
//
#include <hip/hip_runtime.h>
#include <hip/hip_bf16.h>

#define NN 50000
#define NE 800000
#define HH 128
#define SCAN_NB 196  // ceil(50000/256)

typedef short s16x8 __attribute__((ext_vector_type(8)));
typedef float f32x4 __attribute__((ext_vector_type(4)));
typedef unsigned int u32x4 __attribute__((ext_vector_type(4)));
typedef __bf16 bf16x2 __attribute__((ext_vector_type(2)));

__device__ __forceinline__ float u2f(unsigned int v) {
    float f;
    __builtin_memcpy(&f, &v, 4);
    return f;
}
__device__ __forceinline__ float bf2f(unsigned short u) {
    return u2f(((unsigned int)u) << 16);
}
__device__ __forceinline__ unsigned short f2bf_sw(float f) {
    unsigned int x;
    __builtin_memcpy(&x, &f, 4);
    unsigned int r = (x + 0x7fffu + ((x >> 16) & 1u)) >> 16;
    return (unsigned short)r;
}
__device__ __forceinline__ unsigned int f2bf_pk(float a, float b) {
#if __has_builtin(__builtin_amdgcn_cvt_pk_bf16_f32)
    bf16x2 p = __builtin_amdgcn_cvt_pk_bf16_f32(a, b);
    unsigned int u;
    __builtin_memcpy(&u, &p, 4);
    return u;
#else
    return (unsigned int)f2bf_sw(a) | ((unsigned int)f2bf_sw(b) << 16);
#endif
}
__device__ __forceinline__ unsigned short f2bf(float a) {
#if __has_builtin(__builtin_amdgcn_cvt_pk_bf16_f32)
    return (unsigned short)(f2bf_pk(a, a) & 0xffffu);
#else
    return f2bf_sw(a);
#endif
}
__device__ __forceinline__ float silu(float v) {
    return v * __builtin_amdgcn_rcpf(1.f + __expf(-v));
}

// ---- fused prep: all weight transposes + edge-row count ----
__global__ void prep_kernel(
    const float* __restrict__ W_e1, const float* __restrict__ W_e2,
    const float* __restrict__ W_c1, const float* __restrict__ W_n1,
    const float* __restrict__ W_n2, const int* __restrict__ eidx,
    unsigned short* __restrict__ PWT, unsigned short* __restrict__ W2T,
    unsigned short* __restrict__ Wc1T, unsigned short* __restrict__ Wn1T,
    unsigned short* __restrict__ Wn2T, int* __restrict__ counts) {
    int idx = blockIdx.x * 256 + threadIdx.x;
    if (idx < 32768) {
        int cp = idx >> 7, k = idx & 127;
        int srow = (cp < 128) ? k : (128 + k);
        PWT[idx] = f2bf(W_e1[srow * 128 + (cp & 127)]);
    } else if (idx < 49152) {
        int i = idx - 32768, n = i >> 7, k = i & 127;
        W2T[i] = f2bf(W_e2[k * 128 + n]);
    } else if (idx < 65536) {
        int i = idx - 49152, n = i >> 7, k = i & 127;
        Wc1T[i] = f2bf(W_c1[k * 128 + n]);
    } else if (idx < 98304) {
        int i = idx - 65536, n = i >> 8, k = i & 255;
        Wn1T[i] = f2bf(W_n1[k * 128 + n]);
    } else if (idx < 114688) {
        int i = idx - 98304, n = i >> 7, k = i & 127;
        Wn2T[i] = f2bf(W_n2[k * 128 + n]);
    } else if (idx < 114688 + NE) {
        int e = idx - 114688;
        int r = eidx[e];
        r = r < 0 ? 0 : (r >= NN ? NN - 1 : r);
        atomicAdd(&counts[r], 1);
    }
}

// ---- coalesced hierarchical scan (3 tiny kernels) ----
__global__ void k_partial(const int* __restrict__ counts, int* __restrict__ partials) {
    __shared__ int sm[256];
    int idx = blockIdx.x * 256 + threadIdx.x;
    sm[threadIdx.x] = idx < NN ? counts[idx] : 0;
    __syncthreads();
    for (int s = 128; s > 0; s >>= 1) {
        if (threadIdx.x < s) sm[threadIdx.x] += sm[threadIdx.x + s];
        __syncthreads();
    }
    if (threadIdx.x == 0) partials[blockIdx.x] = sm[0];
}
__global__ void k_scanp(const int* __restrict__ partials, int* __restrict__ scanp) {
    __shared__ int sm[256];
    int t = threadIdx.x;
    int v = t < SCAN_NB ? partials[t] : 0;
    sm[t] = v;
    __syncthreads();
    for (int d = 1; d < 256; d <<= 1) {
        int add = t >= d ? sm[t - d] : 0;
        __syncthreads();
        sm[t] += add;
        __syncthreads();
    }
    scanp[t] = sm[t] - v;  // exclusive
}
__global__ void k_offsets(const int* __restrict__ counts, const int* __restrict__ scanp,
                          int* __restrict__ offsets) {
    __shared__ int sm[256];
    int t = threadIdx.x, idx = blockIdx.x * 256 + t;
    int v = idx < NN ? counts[idx] : 0;
    sm[t] = v;
    __syncthreads();
    for (int d = 1; d < 256; d <<= 1) {
        int add = t >= d ? sm[t - d] : 0;
        __syncthreads();
        sm[t] += add;
        __syncthreads();
    }
    if (idx < NN) offsets[idx] = sm[t] - v + scanp[blockIdx.x];
}

// ---- sort edges into CSR slot order; pack (r,c) u16 pair ----
__global__ void k_fill(const int* __restrict__ eidx, const int* __restrict__ offsets,
                       int* __restrict__ cursor, unsigned int* __restrict__ rc) {
    int e = blockIdx.x * 256 + threadIdx.x;
    if (e >= NE) return;
    int r = eidx[e];
    int c = eidx[NE + e];
    r = r < 0 ? 0 : (r >= NN ? NN - 1 : r);
    c = c < 0 ? 0 : (c >= NN ? NN - 1 : c);
    int slot = offsets[r] + atomicAdd(&cursor[r], 1);
    rc[slot] = (unsigned int)r | ((unsigned int)c << 16);
}

// ---- P-GEMM: P1 = bf16(h)@W_top + b1 (folded) f32; P2 = bf16(h)@W_bot -> bf16 ----
__global__ __launch_bounds__(256, 4) void pgemm(
    const float* __restrict__ h, const unsigned short* __restrict__ PWT,
    const float* __restrict__ b1,
    float* __restrict__ P1, unsigned short* __restrict__ P2b) {
    __shared__ unsigned short Alds[64 * 136];
    const int tid = threadIdx.x;
    const int n0 = blockIdx.x * 64;

#pragma unroll
    for (int j = 0; j < 4; j++) {
        int idx = tid + j * 256;
        int e = idx >> 4, ch = idx & 15;
        int node = n0 + e;
        if (node >= NN) node = NN - 1;
        const f32x4* p = (const f32x4*)&h[node * 128 + ch * 8];
        f32x4 a = p[0], b = p[1];
        u32x4 s;
        s[0] = f2bf_pk(a[0], a[1]);
        s[1] = f2bf_pk(a[2], a[3]);
        s[2] = f2bf_pk(b[0], b[1]);
        s[3] = f2bf_pk(b[2], b[3]);
        *(u32x4*)&Alds[e * 136 + ch * 8] = s;
    }
    __syncthreads();

    const int lane = tid & 63;
    const int w = tid >> 6;
    const int ln15 = lane & 15;
    const int q8 = (lane >> 4) * 8, q4 = (lane >> 4) * 4;
    const int cbase = w * 64;

    f32x4 acc[4][4];
#pragma unroll
    for (int et = 0; et < 4; et++)
#pragma unroll
        for (int nt = 0; nt < 4; nt++) acc[et][nt] = (f32x4){0.f, 0.f, 0.f, 0.f};
#pragma unroll
    for (int kk = 0; kk < 4; kk++) {
        int k0 = kk * 32 + q8;
        s16x8 a[4], b[4];
#pragma unroll
        for (int et = 0; et < 4; et++)
            a[et] = *(const s16x8*)&Alds[(et * 16 + ln15) * 136 + k0];
#pragma unroll
        for (int nt = 0; nt < 4; nt++)
            b[nt] = *(const s16x8*)&PWT[(cbase + nt * 16 + ln15) * 128 + k0];
#pragma unroll
        for (int et = 0; et < 4; et++)
#pragma unroll
            for (int nt = 0; nt < 4; nt++)
                acc[et][nt] = __builtin_amdgcn_mfma_f32_16x16x32_bf16(
                    a[et], b[nt], acc[et][nt], 0, 0, 0);
    }
#pragma unroll
    for (int nt = 0; nt < 4; nt++) {
        int cp = cbase + nt * 16 + ln15;
        bool top = cp < 128;
        int col = cp & 127;
        float badd = top ? b1[col] : 0.f;
#pragma unroll
        for (int et = 0; et < 4; et++)
#pragma unroll
            for (int r = 0; r < 4; r++) {
                int row = et * 16 + q4 + r;
                int node = n0 + row;
                if (node >= NN) node = NN - 1;
                float v = acc[et][nt][r] + badd;
                if (top) P1[(size_t)node * 128 + col] = v;
                else     P2b[(size_t)node * 128 + col] = f2bf(v);
            }
    }
}

// ================= edge kernel helpers (two-tile pipeline) =================
// Phase content identical to the 226us R3 kernel; only the schedule changed:
// two 64-edge tiles per block, each barrier region pairs one tile's MFMA
// with the other tile's VALU so both pipes have work (VALU was 53% busy,
// MFMA 10%, phases chip-serialized).

__device__ __forceinline__ void stage_tile(
    unsigned short* mid, int base, int tid,
    const int* rowL, const int* colL, const float* radL, const float* wls,
    const float* __restrict__ P1, const unsigned short* __restrict__ P2b) {
#pragma unroll
    for (int j = 0; j < 4; j++) {
        int idx = tid + j * 256;
        int e = idx >> 4, ch = idx & 15;
        int r = rowL[base + e], c = colL[base + e];
        const f32x4* q1 = (const f32x4*)&P1[(size_t)r * 128 + ch * 8];
        f32x4 a0 = q1[0], a1 = q1[1];
        u32x4 c01 = *(const u32x4*)&P2b[(size_t)c * 128 + ch * 8];
        float rd = radL[base + e];
        int colb = ch * 8;
        u32x4 s;
#pragma unroll
        for (int t = 0; t < 2; t++) {
            float v0 = a0[t * 2]     + u2f(c01[t] << 16)         + rd * wls[colb + t * 2];
            float v1 = a0[t * 2 + 1] + u2f(c01[t] & 0xffff0000u) + rd * wls[colb + t * 2 + 1];
            s[t] = f2bf_pk(silu(v0), silu(v1));
        }
#pragma unroll
        for (int t = 0; t < 2; t++) {
            int cc = colb + 4 + t * 2;
            float v0 = a1[t * 2]     + u2f(c01[t + 2] << 16)         + rd * wls[cc];
            float v1 = a1[t * 2 + 1] + u2f(c01[t + 2] & 0xffff0000u) + rd * wls[cc + 1];
            s[t + 2] = f2bf_pk(silu(v0), silu(v1));
        }
        *(u32x4*)&mid[e * 132 + colb] = s;
    }
}

__device__ __forceinline__ void mm_layer(
    f32x4 (&acc)[4][2], const unsigned short* mid,
    const unsigned short* __restrict__ wt, int tid) {
    const int lane = tid & 63;
    const int w = tid >> 6;
    const int ln15 = lane & 15;
    const int q8 = (lane >> 4) * 8;
    const int nbase = w * 32;
#pragma unroll
    for (int et = 0; et < 4; et++)
#pragma unroll
        for (int nt = 0; nt < 2; nt++) acc[et][nt] = (f32x4){0.f, 0.f, 0.f, 0.f};
#pragma unroll
    for (int kk = 0; kk < 4; kk++) {
        int k0 = kk * 32 + q8;
        s16x8 a[4], b[2];
#pragma unroll
        for (int et = 0; et < 4; et++)
            a[et] = *(const s16x8*)&mid[(et * 16 + ln15) * 132 + k0];
#pragma unroll
        for (int nt = 0; nt < 2; nt++)
            b[nt] = *(const s16x8*)&wt[(nbase + nt * 16 + ln15) * 128 + k0];
#pragma unroll
        for (int et = 0; et < 4; et++)
#pragma unroll
            for (int nt = 0; nt < 2; nt++)
                acc[et][nt] = __builtin_amdgcn_mfma_f32_16x16x32_bf16(
                    a[et], b[nt], acc[et][nt], 0, 0, 0);
    }
}

__device__ __forceinline__ void write_mid2(
    const f32x4 (&acc)[4][2], unsigned short* mid,
    const float* __restrict__ b2, int tid) {
    const int lane = tid & 63;
    const int w = tid >> 6;
    const int ln15 = lane & 15;
    const int q4 = (lane >> 4) * 4;
    const int nbase = w * 32;
#pragma unroll
    for (int nt = 0; nt < 2; nt++) {
        int col = nbase + nt * 16 + ln15;
        float bias = b2[col];
#pragma unroll
        for (int et = 0; et < 4; et++)
#pragma unroll
            for (int r = 0; r < 4; r++) {
                int row = et * 16 + q4 + r;
                mid[row * 132 + col] = f2bf(silu(acc[et][nt][r] + bias));
            }
    }
}

__device__ __forceinline__ void mi_reduce(
    const unsigned short* mid, const int* rowL, int base, int tid,
    float* __restrict__ m_i) {
    int cp2 = (tid & 63) * 2;
    int g = tid >> 6;
    int r0g = g * 16;
    float a0 = 0.f, a1 = 0.f;
    int cur = rowL[base + r0g];
    for (int row = r0g; row < r0g + 16; row++) {
        int rn = rowL[base + row];
        if (rn != cur) {
            atomicAdd(&m_i[(size_t)cur * 128 + cp2], a0);
            atomicAdd(&m_i[(size_t)cur * 128 + cp2 + 1], a1);
            a0 = 0.f; a1 = 0.f;
            cur = rn;
        }
        unsigned int v = *(const unsigned int*)&mid[row * 132 + cp2];
        a0 += u2f(v << 16);
        a1 += u2f(v & 0xffff0000u);
    }
    atomicAdd(&m_i[(size_t)cur * 128 + cp2], a0);
    atomicAdd(&m_i[(size_t)cur * 128 + cp2 + 1], a1);
}

__device__ __forceinline__ void coord_epi(
    const f32x4 (&acc)[4][2], const float* __restrict__ bc1,
    const float* __restrict__ wc2, float* fsumL, int base, int tid) {
    const int lane = tid & 63;
    const int w = tid >> 6;
    const int ln15 = lane & 15;
    const int q4 = (lane >> 4) * 4;
    const int nbase = w * 32;
    float part[4][4];
#pragma unroll
    for (int et = 0; et < 4; et++)
#pragma unroll
        for (int r = 0; r < 4; r++) part[et][r] = 0.f;
#pragma unroll
    for (int nt = 0; nt < 2; nt++) {
        int col = nbase + nt * 16 + ln15;
        float bias = bc1[col];
        float w2 = wc2[col];
#pragma unroll
        for (int et = 0; et < 4; et++)
#pragma unroll
            for (int r = 0; r < 4; r++)
                part[et][r] += silu(acc[et][nt][r] + bias) * w2;
    }
#pragma unroll
    for (int et = 0; et < 4; et++)
#pragma unroll
        for (int r = 0; r < 4; r++) {
            float p = part[et][r];
            p += __shfl_xor(p, 8, 16);
            p += __shfl_xor(p, 4, 16);
            p += __shfl_xor(p, 2, 16);
            p += __shfl_xor(p, 1, 16);
            if (ln15 == 0) atomicAdd(&fsumL[base + et * 16 + q4 + r], p);
        }
}

// ---- edge kernel: 128 CSR-sorted edges per block, two pipelined tiles ----
__global__ __launch_bounds__(256, 4) void edge_kernel(
    const float* __restrict__ P1, const unsigned short* __restrict__ P2b,
    const float* __restrict__ x, const unsigned int* __restrict__ rc,
    const float* __restrict__ W1full,
    const unsigned short* __restrict__ W2T, const float* __restrict__ b2,
    const unsigned short* __restrict__ Wc1T, const float* __restrict__ bc1,
    const float* __restrict__ wc2,
    float* __restrict__ m_i, float* __restrict__ x_acc) {
    __shared__ unsigned short mid_A[64 * 132];  // silu(e1) bf16 tile A; later m_ij A
    __shared__ unsigned short mid_B[64 * 132];  // tile B
    __shared__ float wls[128];
    __shared__ float radL[128], ndxL[128], ndyL[128], ndzL[128], fsumL[128];
    __shared__ int rowL[128], colL[128];

    const int tid = threadIdx.x;
    // bijective XCD swizzle (nwg=6250, 6250%8=2)
    const int nwg = NE / 128;
    const int qq = nwg >> 3, r8 = nwg & 7;
    const int xcd = blockIdx.x & 7, pos = blockIdx.x >> 3;
    const int swz = (xcd < r8 ? xcd * (qq + 1) : r8 * (qq + 1) + (xcd - r8) * qq) + pos;
    const int e0 = swz * 128;

    // setup: both tiles' geometry in parallel (waves 0-1), wls (waves 2-3)
    if (tid < 128) {
        unsigned int pk = rc[e0 + tid];
        int r = pk & 0xffff, c = pk >> 16;
        rowL[tid] = r; colL[tid] = c;
        float dx = x[r * 3 + 0] - x[c * 3 + 0];
        float dy = x[r * 3 + 1] - x[c * 3 + 1];
        float dz = x[r * 3 + 2] - x[c * 3 + 2];
        float d2 = dx * dx + dy * dy + dz * dz;
        float dist = sqrtf(d2);
        float inv = __builtin_amdgcn_rcpf(dist + 1e-8f);
        radL[tid] = d2;
        ndxL[tid] = dx * inv; ndyL[tid] = dy * inv; ndzL[tid] = dz * inv;
        fsumL[tid] = 0.f;
    } else {
        int c = tid - 128;
        wls[c] = W1full[256 * 128 + c];
    }
    __syncthreads();

    f32x4 accA[4][2], accB[4][2];

    // phase1: stage A
    stage_tile(mid_A, 0, tid, rowL, colL, radL, wls, P1, P2b);
    __syncthreads();

    // phase2: e2-MFMA(A)  ||  stage B (VALU + gathers fill MFMA shadow)
    mm_layer(accA, mid_A, W2T, tid);
    stage_tile(mid_B, 64, tid, rowL, colL, radL, wls, P1, P2b);
    __syncthreads();

    // phase3: e2-MFMA(B)  ||  mid2(A) epilogue (silu+pack VALU)
    mm_layer(accB, mid_B, W2T, tid);
    write_mid2(accA, mid_A, b2, tid);
    __syncthreads();

    // phase4: coord-MFMA(A)  ||  mid2(B) epilogue
    mm_layer(accA, mid_A, Wc1T, tid);
    write_mid2(accB, mid_B, b2, tid);
    __syncthreads();

    // phase5: coord-MFMA(B)  ||  E2(A): m_i reduce + coord epilogue + x tail
    mm_layer(accB, mid_B, Wc1T, tid);
    mi_reduce(mid_A, rowL, 0, tid, m_i);
    coord_epi(accA, bc1, wc2, fsumL, 0, tid);
    __syncthreads();
    if (tid < 64) {
        float fs = tanhf(fsumL[tid]) * 0.1f;
        ndxL[tid] *= fs; ndyL[tid] *= fs; ndzL[tid] *= fs;
    }
    __syncthreads();
    if (tid < 64) {
        bool head = (tid == 0) || (rowL[tid] != rowL[tid - 1]);
        if (head) {
            int rn = rowL[tid];
            float ax = 0.f, ay = 0.f, az = 0.f;
            for (int j = tid; j < 64 && rowL[j] == rn; j++) {
                ax += ndxL[j]; ay += ndyL[j]; az += ndzL[j];
            }
            atomicAdd(&x_acc[rn * 3 + 0], ax);
            atomicAdd(&x_acc[rn * 3 + 1], ay);
            atomicAdd(&x_acc[rn * 3 + 2], az);
        }
    }

    // phase6: E2(B)
    mi_reduce(mid_B, rowL, 64, tid, m_i);
    coord_epi(accB, bc1, wc2, fsumL, 64, tid);
    __syncthreads();
    if (tid < 64) {
        float fs = tanhf(fsumL[64 + tid]) * 0.1f;
        ndxL[64 + tid] *= fs; ndyL[64 + tid] *= fs; ndzL[64 + tid] *= fs;
    }
    __syncthreads();
    if (tid < 64) {
        bool head = (tid == 0) || (rowL[64 + tid] != rowL[64 + tid - 1]);
        if (head) {
            int rn = rowL[64 + tid];
            float ax = 0.f, ay = 0.f, az = 0.f;
            for (int j = tid; j < 64 && rowL[64 + j] == rn; j++) {
                ax += ndxL[64 + j]; ay += ndyL[64 + j]; az += ndzL[64 + j];
            }
            atomicAdd(&x_acc[rn * 3 + 0], ax);
            atomicAdd(&x_acc[rn * 3 + 1], ay);
            atomicAdd(&x_acc[rn * 3 + 2], az);
        }
    }
}

// ---- node kernel: 64 nodes per block + fused x update ----
__global__ __launch_bounds__(256, 4) void node_kernel(
    const float* __restrict__ h, const float* __restrict__ m_i,
    const float* __restrict__ x, const float* __restrict__ x_acc,
    const unsigned short* __restrict__ Wn1T, const float* __restrict__ bn1,
    const unsigned short* __restrict__ Wn2T, const float* __restrict__ bn2,
    const float* __restrict__ ln_g, const float* __restrict__ ln_b,
    float* __restrict__ out_h, float* __restrict__ out_x) {
    __shared__ unsigned short Alds[64 * 264];
    unsigned short* mid1 = Alds;
    float* tile = (float*)Alds;

    const int tid = threadIdx.x;
    const int n0 = blockIdx.x * 64;

    if (tid < 192) {
        int i = n0 * 3 + tid;
        if (i < NN * 3) out_x[i] = x[i] + x_acc[i];
    }

    // stage A = [bf16(h) | bf16(m_i)]
#pragma unroll
    for (int i = 0; i < 8; i++) {
        int idx = tid + i * 256;
        int hr = idx >> 4, ch = idx & 15;
        int e = hr >> 1, half = hr & 1;
        int node = n0 + e;
        if (node >= NN) node = NN - 1;
        const float* src = half ? &m_i[(size_t)node * 128 + ch * 8]
                                : &h[(size_t)node * 128 + ch * 8];
        const f32x4* sp = (const f32x4*)src;
        f32x4 f0 = sp[0], f1 = sp[1];
        u32x4 s;
        s[0] = f2bf_pk(f0[0], f0[1]);
        s[1] = f2bf_pk(f0[2], f0[3]);
        s[2] = f2bf_pk(f1[0], f1[1]);
        s[3] = f2bf_pk(f1[2], f1[3]);
        *(u32x4*)&Alds[e * 264 + half * 128 + ch * 8] = s;
    }
    __syncthreads();

    const int lane = tid & 63;
    const int w = tid >> 6;
    const int ln15 = lane & 15;
    const int q8 = (lane >> 4) * 8, q4 = (lane >> 4) * 4;
    const int nbase = w * 32;

    f32x4 acc[4][2];

    // ---- layer n1: K=256
#pragma unroll
    for (int et = 0; et < 4; et++)
#pragma unroll
        for (int nt = 0; nt < 2; nt++) acc[et][nt] = (f32x4){0.f, 0.f, 0.f, 0.f};
#pragma unroll
    for (int kk = 0; kk < 8; kk++) {
        int k0 = kk * 32 + q8;
        s16x8 a[4], b[2];
#pragma unroll
        for (int et = 0; et < 4; et++)
            a[et] = *(const s16x8*)&Alds[(et * 16 + ln15) * 264 + k0];
#pragma unroll
        for (int nt = 0; nt < 2; nt++)
            b[nt] = *(const s16x8*)&Wn1T[(nbase + nt * 16 + ln15) * 256 + k0];
#pragma unroll
        for (int et = 0; et < 4; et++)
#pragma unroll
            for (int nt = 0; nt < 2; nt++)
                acc[et][nt] = __builtin_amdgcn_mfma_f32_16x16x32_bf16(
                    a[et], b[nt], acc[et][nt], 0, 0, 0);
    }
    __syncthreads();  // A dead; mid1 overwrites
#pragma unroll
    for (int nt = 0; nt < 2; nt++) {
        int col = nbase + nt * 16 + ln15;
        float bias = bn1[col];
#pragma unroll
        for (int et = 0; et < 4; et++)
#pragma unroll
            for (int r = 0; r < 4; r++) {
                int row = et * 16 + q4 + r;
                mid1[row * 132 + col] = f2bf(silu(acc[et][nt][r] + bias));
            }
    }
    __syncthreads();

    // ---- layer n2: K=128
#pragma unroll
    for (int et = 0; et < 4; et++)
#pragma unroll
        for (int nt = 0; nt < 2; nt++) acc[et][nt] = (f32x4){0.f, 0.f, 0.f, 0.f};
#pragma unroll
    for (int kk = 0; kk < 4; kk++) {
        int k0 = kk * 32 + q8;
        s16x8 a[4], b[2];
#pragma unroll
        for (int et = 0; et < 4; et++)
            a[et] = *(const s16x8*)&mid1[(et * 16 + ln15) * 132 + k0];
#pragma unroll
        for (int nt = 0; nt < 2; nt++)
            b[nt] = *(const s16x8*)&Wn2T[(nbase + nt * 16 + ln15) * 128 + k0];
#pragma unroll
        for (int et = 0; et < 4; et++)
#pragma unroll
            for (int nt = 0; nt < 2; nt++)
                acc[et][nt] = __builtin_amdgcn_mfma_f32_16x16x32_bf16(
                    a[et], b[nt], acc[et][nt], 0, 0, 0);
    }
    __syncthreads();  // mid1 dead; f32 tile overwrites
#pragma unroll
    for (int nt = 0; nt < 2; nt++) {
        int col = nbase + nt * 16 + ln15;
        float bias = bn2[col];
#pragma unroll
        for (int et = 0; et < 4; et++)
#pragma unroll
            for (int r = 0; r < 4; r++) {
                int row = et * 16 + q4 + r;
                int node = n0 + row;
                int nclamp = node >= NN ? NN - 1 : node;
                float v = acc[et][nt][r] + bias + h[(size_t)nclamp * 128 + col];
                tile[row * 132 + col] = v;
            }
    }
    __syncthreads();

    // ---- LayerNorm: 4 threads/row, interleaved cols
    {
        int row = tid >> 2;
        int q = tid & 3;
        float s = 0.f, s2 = 0.f;
#pragma unroll
        for (int c = 0; c < 32; c++) {
            float v = tile[row * 132 + q + c * 4];
            s += v; s2 += v * v;
        }
        s += __shfl_xor(s, 1, 4);  s2 += __shfl_xor(s2, 1, 4);
        s += __shfl_xor(s, 2, 4);  s2 += __shfl_xor(s2, 2, 4);
        float mean = s * (1.f / 128.f);
        float var = s2 * (1.f / 128.f) - mean * mean;
        float rs = rsqrtf(var + 1e-5f);
        int node = n0 + row;
        if (node < NN) {
#pragma unroll
            for (int c = 0; c < 32; c++) {
                int col = q + c * 4;
                float v = (tile[row * 132 + col] - mean) * rs * ln_g[col] + ln_b[col];
                out_h[(size_t)node * 128 + col] = v;
            }
        }
    }
}

extern "C" void kernel_launch(void* const* d_in, const int* in_sizes, int n_in,
                              void* d_out, int out_size, void* d_ws, size_t ws_size,
                              hipStream_t stream) {
    const float* h    = (const float*)d_in[0];
    const float* x    = (const float*)d_in[1];
    const int* eidx   = (const int*)d_in[2];
    const float* W_e1 = (const float*)d_in[3];
    const float* b_e1 = (const float*)d_in[4];
    const float* W_e2 = (const float*)d_in[5];
    const float* b_e2 = (const float*)d_in[6];
    const float* W_c1 = (const float*)d_in[7];
    const float* b_c1 = (const float*)d_in[8];
    const float* W_c2 = (const float*)d_in[9];
    const float* W_n1 = (const float*)d_in[10];
    const float* b_n1 = (const float*)d_in[11];
    const float* W_n2 = (const float*)d_in[12];
    const float* b_n2 = (const float*)d_in[13];
    const float* ln_g = (const float*)d_in[14];
    const float* ln_b = (const float*)d_in[15];

    float* out_h = (float*)d_out;
    float* out_x = out_h + NN * HH;

    char* ws = (char*)d_ws;
    float* m_i    = (float*)ws;                       // 25,600,000 (zero)
    float* x_acc  = (float*)(ws + 25600000);          //    600,000 (zero)
    int* counts   = (int*)(ws + 26200000);            //    200,000 (zero)
    int* cursor   = (int*)(ws + 26400000);            //    200,000 (zero)
    int* offsets  = (int*)(ws + 26600000);            //    200,000
    int* partials = (int*)(ws + 26800000);            //      1,024
    int* scanp    = (int*)(ws + 26801024);            //      1,024
    unsigned int* rc = (unsigned int*)(ws + 26802048);       //  3,200,000
    float* P1 = (float*)(ws + 30002048);                     // 25,600,000
    unsigned short* P2b = (unsigned short*)(ws + 55602048);  // 12,800,000
    unsigned short* PWT  = (unsigned short*)(ws + 81202048); //     65,536
    unsigned short* W2T  = (unsigned short*)(ws + 81267584); //     32,768
    unsigned short* Wc1T = (unsigned short*)(ws + 81300352); //     32,768
    unsigned short* Wn1T = (unsigned short*)(ws + 81333120); //     65,536
    unsigned short* Wn2T = (unsigned short*)(ws + 81398656); //     32,768

    hipMemsetAsync(ws, 0, 26800000, stream);  // m_i + x_acc + counts + cursor

    prep_kernel<<<(114688 + NE + 255) / 256, 256, 0, stream>>>(
        W_e1, W_e2, W_c1, W_n1, W_n2, eidx, PWT, W2T, Wc1T, Wn1T, Wn2T, counts);
    k_partial<<<SCAN_NB, 256, 0, stream>>>(counts, partials);
    k_scanp<<<1, 256, 0, stream>>>(partials, scanp);
    k_offsets<<<SCAN_NB, 256, 0, stream>>>(counts, scanp, offsets);
    k_fill<<<(NE + 255) / 256, 256, 0, stream>>>(eidx, offsets, cursor, rc);
    pgemm<<<(NN + 63) / 64, 256, 0, stream>>>(h, PWT, b_e1, P1, P2b);

    edge_kernel<<<NE / 128, 256, 0, stream>>>(P1, P2b, x, rc, W_e1, W2T, b_e2,
                                              Wc1T, b_c1, W_c2, m_i, x_acc);
    node_kernel<<<(NN + 63) / 64, 256, 0, stream>>>(
        h, m_i, x, x_acc, Wn1T, b_n1, Wn2T, b_n2, ln_g, ln_b, out_h, out_x);
}

// Round 6
// 426.831 us; speedup vs baseline: 1.2904x; 1.2904x over previous
//
#include <hip/hip_runtime.h>
#include <hip/hip_bf16.h>

#define NN 50000
#define NE 800000
#define HH 128
#define SCAN_NB 196  // ceil(50000/256)

typedef short s16x8 __attribute__((ext_vector_type(8)));
typedef float f32x4 __attribute__((ext_vector_type(4)));
typedef unsigned int u32x4 __attribute__((ext_vector_type(4)));
typedef unsigned int u32x2 __attribute__((ext_vector_type(2)));
typedef __bf16 bf16x2 __attribute__((ext_vector_type(2)));

__device__ __forceinline__ float u2f(unsigned int v) {
    float f;
    __builtin_memcpy(&f, &v, 4);
    return f;
}
__device__ __forceinline__ float bf2f(unsigned short u) {
    return u2f(((unsigned int)u) << 16);
}
__device__ __forceinline__ unsigned short f2bf_sw(float f) {
    unsigned int x;
    __builtin_memcpy(&x, &f, 4);
    unsigned int r = (x + 0x7fffu + ((x >> 16) & 1u)) >> 16;
    return (unsigned short)r;
}
__device__ __forceinline__ unsigned int f2bf_pk(float a, float b) {
#if __has_builtin(__builtin_amdgcn_cvt_pk_bf16_f32)
    bf16x2 p = __builtin_amdgcn_cvt_pk_bf16_f32(a, b);
    unsigned int u;
    __builtin_memcpy(&u, &p, 4);
    return u;
#else
    return (unsigned int)f2bf_sw(a) | ((unsigned int)f2bf_sw(b) << 16);
#endif
}
__device__ __forceinline__ unsigned short f2bf(float a) {
#if __has_builtin(__builtin_amdgcn_cvt_pk_bf16_f32)
    return (unsigned short)(f2bf_pk(a, a) & 0xffffu);
#else
    return f2bf_sw(a);
#endif
}
__device__ __forceinline__ float silu(float v) {
    return v * __builtin_amdgcn_rcpf(1.f + __expf(-v));
}

// ---- fused prep: all weight transposes + edge-row count ----
__global__ void prep_kernel(
    const float* __restrict__ W_e1, const float* __restrict__ W_e2,
    const float* __restrict__ W_c1, const float* __restrict__ W_n1,
    const float* __restrict__ W_n2, const int* __restrict__ eidx,
    unsigned short* __restrict__ PWT, unsigned short* __restrict__ W2T,
    unsigned short* __restrict__ Wc1T, unsigned short* __restrict__ Wn1T,
    unsigned short* __restrict__ Wn2T, int* __restrict__ counts) {
    int idx = blockIdx.x * 256 + threadIdx.x;
    if (idx < 32768) {
        int cp = idx >> 7, k = idx & 127;
        int srow = (cp < 128) ? k : (128 + k);
        PWT[idx] = f2bf(W_e1[srow * 128 + (cp & 127)]);
    } else if (idx < 49152) {
        int i = idx - 32768, n = i >> 7, k = i & 127;
        W2T[i] = f2bf(W_e2[k * 128 + n]);
    } else if (idx < 65536) {
        int i = idx - 49152, n = i >> 7, k = i & 127;
        Wc1T[i] = f2bf(W_c1[k * 128 + n]);
    } else if (idx < 98304) {
        int i = idx - 65536, n = i >> 8, k = i & 255;
        Wn1T[i] = f2bf(W_n1[k * 128 + n]);
    } else if (idx < 114688) {
        int i = idx - 98304, n = i >> 7, k = i & 127;
        Wn2T[i] = f2bf(W_n2[k * 128 + n]);
    } else if (idx < 114688 + NE) {
        int e = idx - 114688;
        int r = eidx[e];
        r = r < 0 ? 0 : (r >= NN ? NN - 1 : r);
        atomicAdd(&counts[r], 1);
    }
}

// ---- coalesced hierarchical scan (3 tiny kernels) ----
__global__ void k_partial(const int* __restrict__ counts, int* __restrict__ partials) {
    __shared__ int sm[256];
    int idx = blockIdx.x * 256 + threadIdx.x;
    sm[threadIdx.x] = idx < NN ? counts[idx] : 0;
    __syncthreads();
    for (int s = 128; s > 0; s >>= 1) {
        if (threadIdx.x < s) sm[threadIdx.x] += sm[threadIdx.x + s];
        __syncthreads();
    }
    if (threadIdx.x == 0) partials[blockIdx.x] = sm[0];
}
__global__ void k_scanp(const int* __restrict__ partials, int* __restrict__ scanp) {
    __shared__ int sm[256];
    int t = threadIdx.x;
    int v = t < SCAN_NB ? partials[t] : 0;
    sm[t] = v;
    __syncthreads();
    for (int d = 1; d < 256; d <<= 1) {
        int add = t >= d ? sm[t - d] : 0;
        __syncthreads();
        sm[t] += add;
        __syncthreads();
    }
    scanp[t] = sm[t] - v;  // exclusive
}
__global__ void k_offsets(const int* __restrict__ counts, const int* __restrict__ scanp,
                          int* __restrict__ offsets) {
    __shared__ int sm[256];
    int t = threadIdx.x, idx = blockIdx.x * 256 + t;
    int v = idx < NN ? counts[idx] : 0;
    sm[t] = v;
    __syncthreads();
    for (int d = 1; d < 256; d <<= 1) {
        int add = t >= d ? sm[t - d] : 0;
        __syncthreads();
        sm[t] += add;
        __syncthreads();
    }
    if (idx < NN) offsets[idx] = sm[t] - v + scanp[blockIdx.x];
}

// ---- sort edges into CSR slot order; pack (r,c) u16 pair ----
__global__ void k_fill(const int* __restrict__ eidx, const int* __restrict__ offsets,
                       int* __restrict__ cursor, unsigned int* __restrict__ rc) {
    int e = blockIdx.x * 256 + threadIdx.x;
    if (e >= NE) return;
    int r = eidx[e];
    int c = eidx[NE + e];
    r = r < 0 ? 0 : (r >= NN ? NN - 1 : r);
    c = c < 0 ? 0 : (c >= NN ? NN - 1 : c);
    int slot = offsets[r] + atomicAdd(&cursor[r], 1);
    rc[slot] = (unsigned int)r | ((unsigned int)c << 16);
}

// ---- P-GEMM: P1 = bf16(h)@W_top + b1 (folded) f32; P2 = bf16(h)@W_bot -> bf16 ----
// Swapped-operand MFMA (mfma(b,a)): thread holds 4 CONSECUTIVE output cols of
// one node row -> vector stores (16 instead of 64 scalar).
__global__ __launch_bounds__(256, 4) void pgemm(
    const float* __restrict__ h, const unsigned short* __restrict__ PWT,
    const float* __restrict__ b1,
    float* __restrict__ P1, unsigned short* __restrict__ P2b) {
    __shared__ unsigned short Alds[64 * 136];
    const int tid = threadIdx.x;
    const int n0 = blockIdx.x * 64;

#pragma unroll
    for (int j = 0; j < 4; j++) {
        int idx = tid + j * 256;
        int e = idx >> 4, ch = idx & 15;
        int node = n0 + e;
        if (node >= NN) node = NN - 1;
        const f32x4* p = (const f32x4*)&h[node * 128 + ch * 8];
        f32x4 a = p[0], b = p[1];
        u32x4 s;
        s[0] = f2bf_pk(a[0], a[1]);
        s[1] = f2bf_pk(a[2], a[3]);
        s[2] = f2bf_pk(b[0], b[1]);
        s[3] = f2bf_pk(b[2], b[3]);
        *(u32x4*)&Alds[e * 136 + ch * 8] = s;
    }
    __syncthreads();

    const int lane = tid & 63;
    const int w = tid >> 6;
    const int ln15 = lane & 15;
    const int q8 = (lane >> 4) * 8, q4 = (lane >> 4) * 4;
    const int cbase = w * 64;

    f32x4 acc[4][4];
#pragma unroll
    for (int et = 0; et < 4; et++)
#pragma unroll
        for (int nt = 0; nt < 4; nt++) acc[et][nt] = (f32x4){0.f, 0.f, 0.f, 0.f};
#pragma unroll
    for (int kk = 0; kk < 4; kk++) {
        int k0 = kk * 32 + q8;
        s16x8 a[4], b[4];
#pragma unroll
        for (int et = 0; et < 4; et++)
            a[et] = *(const s16x8*)&Alds[(et * 16 + ln15) * 136 + k0];
#pragma unroll
        for (int nt = 0; nt < 4; nt++)
            b[nt] = *(const s16x8*)&PWT[(cbase + nt * 16 + ln15) * 128 + k0];
#pragma unroll
        for (int et = 0; et < 4; et++)
#pragma unroll
            for (int nt = 0; nt < 4; nt++)
                acc[et][nt] = __builtin_amdgcn_mfma_f32_16x16x32_bf16(
                    b[nt], a[et], acc[et][nt], 0, 0, 0);  // swapped: D[cp][node]
    }
    // epilogue: thread holds cols cp4..cp4+3 for node n0+et*16+ln15
#pragma unroll
    for (int nt = 0; nt < 4; nt++) {
        int cp4 = cbase + nt * 16 + q4;
        bool top = cp4 < 128;
        int col4 = cp4 & 127;
        f32x4 badd = top ? *(const f32x4*)&b1[col4] : (f32x4){0.f, 0.f, 0.f, 0.f};
#pragma unroll
        for (int et = 0; et < 4; et++) {
            int node = n0 + et * 16 + ln15;
            if (node >= NN) node = NN - 1;
            f32x4 v;
#pragma unroll
            for (int r = 0; r < 4; r++) v[r] = acc[et][nt][r] + badd[r];
            if (top) {
                *(f32x4*)&P1[(size_t)node * 128 + col4] = v;
            } else {
                u32x2 s;
                s[0] = f2bf_pk(v[0], v[1]);
                s[1] = f2bf_pk(v[2], v[3]);
                *(u32x2*)&P2b[(size_t)node * 128 + col4] = s;
            }
        }
    }
}

// ---- edge kernel: 64 CSR-sorted edge slots per block, 256 threads ----
// R3 structure (226us) + swapped-operand MFMA for e2/coord: D[col][edge]
// gives each thread 4 consecutive cols of one edge -> packed b64 mid2
// writes (8 vs 32 b16), float4 bias loads, coord reduce = 2 shfl (vs 64).
__global__ __launch_bounds__(256, 4) void edge_kernel(
    const float* __restrict__ P1, const unsigned short* __restrict__ P2b,
    const float* __restrict__ x, const unsigned int* __restrict__ rc,
    const float* __restrict__ W1full,
    const unsigned short* __restrict__ W2T, const float* __restrict__ b2,
    const unsigned short* __restrict__ Wc1T, const float* __restrict__ bc1,
    const float* __restrict__ wc2,
    float* __restrict__ m_i, float* __restrict__ x_acc) {
    __shared__ unsigned short mid1[64 * 132];  // silu(e1) bf16; later m_ij
    __shared__ float wls[128];
    __shared__ float rad[64], ndx[64], ndy[64], ndz[64], fsum[64];
    __shared__ int rowA[64], colA[64];

    const int tid = threadIdx.x;
    // bijective XCD swizzle (nwg=12500, 12500%8=4)
    const int nwg = NE / 64;
    const int qq = nwg >> 3, r8 = nwg & 7;
    const int xcd = blockIdx.x & 7, pos = blockIdx.x >> 3;
    const int swz = (xcd < r8 ? xcd * (qq + 1) : r8 * (qq + 1) + (xcd - r8) * qq) + pos;
    const int e0 = swz * 64;

    if (tid < 64) {
        unsigned int pk = rc[e0 + tid];
        int r = pk & 0xffff, c = pk >> 16;
        rowA[tid] = r; colA[tid] = c;
        float dx = x[r * 3 + 0] - x[c * 3 + 0];
        float dy = x[r * 3 + 1] - x[c * 3 + 1];
        float dz = x[r * 3 + 2] - x[c * 3 + 2];
        float d2 = dx * dx + dy * dy + dz * dz;
        float dist = sqrtf(d2);
        float inv = __builtin_amdgcn_rcpf(dist + 1e-8f);
        rad[tid] = d2;
        ndx[tid] = dx * inv; ndy[tid] = dy * inv; ndz[tid] = dz * inv;
        fsum[tid] = 0.f;
    } else if (tid >= 128 && tid < 256) {
        int c = tid - 128;
        wls[c] = W1full[256 * 128 + c];
    }
    __syncthreads();

    // stage mid1 = silu(P1[row](+b1) + P2b[col] + rad*wl); P2 is bf16-packed
#pragma unroll
    for (int j = 0; j < 4; j++) {
        int idx = tid + j * 256;
        int e = idx >> 4, ch = idx & 15;
        int r = rowA[e], c = colA[e];
        const f32x4* q1 = (const f32x4*)&P1[(size_t)r * 128 + ch * 8];
        f32x4 a0 = q1[0], a1 = q1[1];
        u32x4 c01 = *(const u32x4*)&P2b[(size_t)c * 128 + ch * 8];
        float rd = rad[e];
        int colb = ch * 8;
        u32x4 s;
#pragma unroll
        for (int t = 0; t < 2; t++) {
            float v0 = a0[t * 2]     + u2f(c01[t] << 16)         + rd * wls[colb + t * 2];
            float v1 = a0[t * 2 + 1] + u2f(c01[t] & 0xffff0000u) + rd * wls[colb + t * 2 + 1];
            s[t] = f2bf_pk(silu(v0), silu(v1));
        }
#pragma unroll
        for (int t = 0; t < 2; t++) {
            int cc = colb + 4 + t * 2;
            float v0 = a1[t * 2]     + u2f(c01[t + 2] << 16)         + rd * wls[cc];
            float v1 = a1[t * 2 + 1] + u2f(c01[t + 2] & 0xffff0000u) + rd * wls[cc + 1];
            s[t + 2] = f2bf_pk(silu(v0), silu(v1));
        }
        *(u32x4*)&mid1[e * 132 + colb] = s;
    }
    __syncthreads();

    const int lane = tid & 63;
    const int w = tid >> 6;
    const int ln15 = lane & 15;
    const int q8 = (lane >> 4) * 8, q4 = (lane >> 4) * 4;
    const int nbase = w * 32;

    f32x4 acc[4][2];

    // ---- layer e2 (swapped): acc[et][nt] = D[col-run][edge]
#pragma unroll
    for (int et = 0; et < 4; et++)
#pragma unroll
        for (int nt = 0; nt < 2; nt++) acc[et][nt] = (f32x4){0.f, 0.f, 0.f, 0.f};
#pragma unroll
    for (int kk = 0; kk < 4; kk++) {
        int k0 = kk * 32 + q8;
        s16x8 a[4], b[2];
#pragma unroll
        for (int et = 0; et < 4; et++)
            a[et] = *(const s16x8*)&mid1[(et * 16 + ln15) * 132 + k0];
#pragma unroll
        for (int nt = 0; nt < 2; nt++)
            b[nt] = *(const s16x8*)&W2T[(nbase + nt * 16 + ln15) * 128 + k0];
#pragma unroll
        for (int et = 0; et < 4; et++)
#pragma unroll
            for (int nt = 0; nt < 2; nt++)
                acc[et][nt] = __builtin_amdgcn_mfma_f32_16x16x32_bf16(
                    b[nt], a[et], acc[et][nt], 0, 0, 0);
    }
    __syncthreads();  // all mid1 reads done; reuse as mid2
    unsigned short* mid2 = mid1;
    // packed epilogue: edge = et*16+ln15, cols = nbase+nt*16+q4 .. +3
#pragma unroll
    for (int et = 0; et < 4; et++) {
        int edge = et * 16 + ln15;
#pragma unroll
        for (int nt = 0; nt < 2; nt++) {
            int colb4 = nbase + nt * 16 + q4;
            f32x4 bias = *(const f32x4*)&b2[colb4];
            u32x2 s;
            s[0] = f2bf_pk(silu(acc[et][nt][0] + bias[0]),
                           silu(acc[et][nt][1] + bias[1]));
            s[1] = f2bf_pk(silu(acc[et][nt][2] + bias[2]),
                           silu(acc[et][nt][3] + bias[3]));
            *(u32x2*)&mid2[edge * 132 + colb4] = s;
        }
    }
    __syncthreads();

    // ---- coord layer (swapped): c1 tile D[col-run][edge]
#pragma unroll
    for (int et = 0; et < 4; et++)
#pragma unroll
        for (int nt = 0; nt < 2; nt++) acc[et][nt] = (f32x4){0.f, 0.f, 0.f, 0.f};
#pragma unroll
    for (int kk = 0; kk < 4; kk++) {
        int k0 = kk * 32 + q8;
        s16x8 a[4], b[2];
#pragma unroll
        for (int et = 0; et < 4; et++)
            a[et] = *(const s16x8*)&mid2[(et * 16 + ln15) * 132 + k0];
#pragma unroll
        for (int nt = 0; nt < 2; nt++)
            b[nt] = *(const s16x8*)&Wc1T[(nbase + nt * 16 + ln15) * 128 + k0];
#pragma unroll
        for (int et = 0; et < 4; et++)
#pragma unroll
            for (int nt = 0; nt < 2; nt++)
                acc[et][nt] = __builtin_amdgcn_mfma_f32_16x16x32_bf16(
                    b[nt], a[et], acc[et][nt], 0, 0, 0);
    }

    // ---- m_i segment-reduce from mid2 (u32 col-pairs; 4 groups of 16 rows) ----
    {
        int cp2 = (tid & 63) * 2;
        int g = tid >> 6;       // 0..3
        int r0g = g * 16;
        float a0 = 0.f, a1 = 0.f;
        int cur = rowA[r0g];
        for (int row = r0g; row < r0g + 16; row++) {
            int rn = rowA[row];
            if (rn != cur) {
                atomicAdd(&m_i[(size_t)cur * 128 + cp2], a0);
                atomicAdd(&m_i[(size_t)cur * 128 + cp2 + 1], a1);
                a0 = 0.f; a1 = 0.f;
                cur = rn;
            }
            unsigned int v = *(const unsigned int*)&mid2[row * 132 + cp2];
            a0 += u2f(v << 16);
            a1 += u2f(v & 0xffff0000u);
        }
        atomicAdd(&m_i[(size_t)cur * 128 + cp2], a0);
        atomicAdd(&m_i[(size_t)cur * 128 + cp2 + 1], a1);
    }

    // ---- coord epilogue: fs = tanh(c1 . wc2) * 0.1  (per-edge local sum)
    {
#pragma unroll
        for (int et = 0; et < 4; et++) {
            float p = 0.f;
#pragma unroll
            for (int nt = 0; nt < 2; nt++) {
                int colb4 = nbase + nt * 16 + q4;
                f32x4 bias = *(const f32x4*)&bc1[colb4];
                f32x4 w2v  = *(const f32x4*)&wc2[colb4];
#pragma unroll
                for (int r = 0; r < 4; r++)
                    p += silu(acc[et][nt][r] + bias[r]) * w2v[r];
            }
            p += __shfl_xor(p, 16, 64);
            p += __shfl_xor(p, 32, 64);
            if ((lane >> 4) == 0) atomicAdd(&fsum[et * 16 + ln15], p);
        }
    }
    __syncthreads();
    if (tid < 64) {
        float fs = tanhf(fsum[tid]) * 0.1f;
        ndx[tid] *= fs; ndy[tid] *= fs; ndz[tid] *= fs;
    }
    __syncthreads();
    if (tid < 64) {
        bool head = (tid == 0) || (rowA[tid] != rowA[tid - 1]);
        if (head) {
            int rn = rowA[tid];
            float ax = 0.f, ay = 0.f, az = 0.f;
            for (int j = tid; j < 64 && rowA[j] == rn; j++) {
                ax += ndx[j]; ay += ndy[j]; az += ndz[j];
            }
            atomicAdd(&x_acc[rn * 3 + 0], ax);
            atomicAdd(&x_acc[rn * 3 + 1], ay);
            atomicAdd(&x_acc[rn * 3 + 2], az);
        }
    }
}

// ---- node kernel: 64 nodes per block + fused x update (swapped MFMA) ----
__global__ __launch_bounds__(256, 4) void node_kernel(
    const float* __restrict__ h, const float* __restrict__ m_i,
    const float* __restrict__ x, const float* __restrict__ x_acc,
    const unsigned short* __restrict__ Wn1T, const float* __restrict__ bn1,
    const unsigned short* __restrict__ Wn2T, const float* __restrict__ bn2,
    const float* __restrict__ ln_g, const float* __restrict__ ln_b,
    float* __restrict__ out_h, float* __restrict__ out_x) {
    __shared__ unsigned short Alds[64 * 264];
    unsigned short* mid1 = Alds;
    float* tile = (float*)Alds;

    const int tid = threadIdx.x;
    const int n0 = blockIdx.x * 64;

    if (tid < 192) {
        int i = n0 * 3 + tid;
        if (i < NN * 3) out_x[i] = x[i] + x_acc[i];
    }

    // stage A = [bf16(h) | bf16(m_i)]
#pragma unroll
    for (int i = 0; i < 8; i++) {
        int idx = tid + i * 256;
        int hr = idx >> 4, ch = idx & 15;
        int e = hr >> 1, half = hr & 1;
        int node = n0 + e;
        if (node >= NN) node = NN - 1;
        const float* src = half ? &m_i[(size_t)node * 128 + ch * 8]
                                : &h[(size_t)node * 128 + ch * 8];
        const f32x4* sp = (const f32x4*)src;
        f32x4 f0 = sp[0], f1 = sp[1];
        u32x4 s;
        s[0] = f2bf_pk(f0[0], f0[1]);
        s[1] = f2bf_pk(f0[2], f0[3]);
        s[2] = f2bf_pk(f1[0], f1[1]);
        s[3] = f2bf_pk(f1[2], f1[3]);
        *(u32x4*)&Alds[e * 264 + half * 128 + ch * 8] = s;
    }
    __syncthreads();

    const int lane = tid & 63;
    const int w = tid >> 6;
    const int ln15 = lane & 15;
    const int q8 = (lane >> 4) * 8, q4 = (lane >> 4) * 4;
    const int nbase = w * 32;

    f32x4 acc[4][2];

    // ---- layer n1: K=256 (swapped)
#pragma unroll
    for (int et = 0; et < 4; et++)
#pragma unroll
        for (int nt = 0; nt < 2; nt++) acc[et][nt] = (f32x4){0.f, 0.f, 0.f, 0.f};
#pragma unroll
    for (int kk = 0; kk < 8; kk++) {
        int k0 = kk * 32 + q8;
        s16x8 a[4], b[2];
#pragma unroll
        for (int et = 0; et < 4; et++)
            a[et] = *(const s16x8*)&Alds[(et * 16 + ln15) * 264 + k0];
#pragma unroll
        for (int nt = 0; nt < 2; nt++)
            b[nt] = *(const s16x8*)&Wn1T[(nbase + nt * 16 + ln15) * 256 + k0];
#pragma unroll
        for (int et = 0; et < 4; et++)
#pragma unroll
            for (int nt = 0; nt < 2; nt++)
                acc[et][nt] = __builtin_amdgcn_mfma_f32_16x16x32_bf16(
                    b[nt], a[et], acc[et][nt], 0, 0, 0);
    }
    __syncthreads();  // A dead; mid1 overwrites
#pragma unroll
    for (int et = 0; et < 4; et++) {
        int row = et * 16 + ln15;
#pragma unroll
        for (int nt = 0; nt < 2; nt++) {
            int colb4 = nbase + nt * 16 + q4;
            f32x4 bias = *(const f32x4*)&bn1[colb4];
            u32x2 s;
            s[0] = f2bf_pk(silu(acc[et][nt][0] + bias[0]),
                           silu(acc[et][nt][1] + bias[1]));
            s[1] = f2bf_pk(silu(acc[et][nt][2] + bias[2]),
                           silu(acc[et][nt][3] + bias[3]));
            *(u32x2*)&mid1[row * 132 + colb4] = s;
        }
    }
    __syncthreads();

    // ---- layer n2: K=128 (swapped)
#pragma unroll
    for (int et = 0; et < 4; et++)
#pragma unroll
        for (int nt = 0; nt < 2; nt++) acc[et][nt] = (f32x4){0.f, 0.f, 0.f, 0.f};
#pragma unroll
    for (int kk = 0; kk < 4; kk++) {
        int k0 = kk * 32 + q8;
        s16x8 a[4], b[2];
#pragma unroll
        for (int et = 0; et < 4; et++)
            a[et] = *(const s16x8*)&mid1[(et * 16 + ln15) * 132 + k0];
#pragma unroll
        for (int nt = 0; nt < 2; nt++)
            b[nt] = *(const s16x8*)&Wn2T[(nbase + nt * 16 + ln15) * 128 + k0];
#pragma unroll
        for (int et = 0; et < 4; et++)
#pragma unroll
            for (int nt = 0; nt < 2; nt++)
                acc[et][nt] = __builtin_amdgcn_mfma_f32_16x16x32_bf16(
                    b[nt], a[et], acc[et][nt], 0, 0, 0);
    }
    __syncthreads();  // mid1 dead; f32 tile overwrites
#pragma unroll
    for (int et = 0; et < 4; et++) {
        int row = et * 16 + ln15;
        int node = n0 + row;
        int nclamp = node >= NN ? NN - 1 : node;
#pragma unroll
        for (int nt = 0; nt < 2; nt++) {
            int colb4 = nbase + nt * 16 + q4;
            f32x4 bias = *(const f32x4*)&bn2[colb4];
            f32x4 hv = *(const f32x4*)&h[(size_t)nclamp * 128 + colb4];
            f32x4 v;
#pragma unroll
            for (int r = 0; r < 4; r++) v[r] = acc[et][nt][r] + bias[r] + hv[r];
            *(f32x4*)&tile[row * 132 + colb4] = v;
        }
    }
    __syncthreads();

    // ---- LayerNorm: 4 threads/row, interleaved cols
    {
        int row = tid >> 2;
        int q = tid & 3;
        float s = 0.f, s2 = 0.f;
#pragma unroll
        for (int c = 0; c < 32; c++) {
            float v = tile[row * 132 + q + c * 4];
            s += v; s2 += v * v;
        }
        s += __shfl_xor(s, 1, 4);  s2 += __shfl_xor(s2, 1, 4);
        s += __shfl_xor(s, 2, 4);  s2 += __shfl_xor(s2, 2, 4);
        float mean = s * (1.f / 128.f);
        float var = s2 * (1.f / 128.f) - mean * mean;
        float rs = rsqrtf(var + 1e-5f);
        int node = n0 + row;
        if (node < NN) {
#pragma unroll
            for (int c = 0; c < 32; c++) {
                int col = q + c * 4;
                float v = (tile[row * 132 + col] - mean) * rs * ln_g[col] + ln_b[col];
                out_h[(size_t)node * 128 + col] = v;
            }
        }
    }
}

extern "C" void kernel_launch(void* const* d_in, const int* in_sizes, int n_in,
                              void* d_out, int out_size, void* d_ws, size_t ws_size,
                              hipStream_t stream) {
    const float* h    = (const float*)d_in[0];
    const float* x    = (const float*)d_in[1];
    const int* eidx   = (const int*)d_in[2];
    const float* W_e1 = (const float*)d_in[3];
    const float* b_e1 = (const float*)d_in[4];
    const float* W_e2 = (const float*)d_in[5];
    const float* b_e2 = (const float*)d_in[6];
    const float* W_c1 = (const float*)d_in[7];
    const float* b_c1 = (const float*)d_in[8];
    const float* W_c2 = (const float*)d_in[9];
    const float* W_n1 = (const float*)d_in[10];
    const float* b_n1 = (const float*)d_in[11];
    const float* W_n2 = (const float*)d_in[12];
    const float* b_n2 = (const float*)d_in[13];
    const float* ln_g = (const float*)d_in[14];
    const float* ln_b = (const float*)d_in[15];

    float* out_h = (float*)d_out;
    float* out_x = out_h + NN * HH;

    char* ws = (char*)d_ws;
    float* m_i    = (float*)ws;                       // 25,600,000 (zero)
    float* x_acc  = (float*)(ws + 25600000);          //    600,000 (zero)
    int* counts   = (int*)(ws + 26200000);            //    200,000 (zero)
    int* cursor   = (int*)(ws + 26400000);            //    200,000 (zero)
    int* offsets  = (int*)(ws + 26600000);            //    200,000
    int* partials = (int*)(ws + 26800000);            //      1,024
    int* scanp    = (int*)(ws + 26801024);            //      1,024
    unsigned int* rc = (unsigned int*)(ws + 26802048);       //  3,200,000
    float* P1 = (float*)(ws + 30002048);                     // 25,600,000
    unsigned short* P2b = (unsigned short*)(ws + 55602048);  // 12,800,000
    unsigned short* PWT  = (unsigned short*)(ws + 81202048); //     65,536
    unsigned short* W2T  = (unsigned short*)(ws + 81267584); //     32,768
    unsigned short* Wc1T = (unsigned short*)(ws + 81300352); //     32,768
    unsigned short* Wn1T = (unsigned short*)(ws + 81333120); //     65,536
    unsigned short* Wn2T = (unsigned short*)(ws + 81398656); //     32,768

    hipMemsetAsync(ws, 0, 26800000, stream);  // m_i + x_acc + counts + cursor

    prep_kernel<<<(114688 + NE + 255) / 256, 256, 0, stream>>>(
        W_e1, W_e2, W_c1, W_n1, W_n2, eidx, PWT, W2T, Wc1T, Wn1T, Wn2T, counts);
    k_partial<<<SCAN_NB, 256, 0, stream>>>(counts, partials);
    k_scanp<<<1, 256, 0, stream>>>(partials, scanp);
    k_offsets<<<SCAN_NB, 256, 0, stream>>>(counts, scanp, offsets);
    k_fill<<<(NE + 255) / 256, 256, 0, stream>>>(eidx, offsets, cursor, rc);
    pgemm<<<(NN + 63) / 64, 256, 0, stream>>>(h, PWT, b_e1, P1, P2b);

    edge_kernel<<<NE / 64, 256, 0, stream>>>(P1, P2b, x, rc, W_e1, W2T, b_e2,
                                             Wc1T, b_c1, W_c2, m_i, x_acc);
    node_kernel<<<(NN + 63) / 64, 256, 0, stream>>>(
        h, m_i, x, x_acc, Wn1T, b_n1, Wn2T, b_n2, ln_g, ln_b, out_h, out_x);
}